// Round 13
// baseline (175.106 us; speedup 1.0000x reference)
//
#include <hip/hip_runtime.h>
#include <hip/hip_bf16.h>
#include <stdint.h>

#define NP 30000
#define BBINS 80
#define INCH 16
#define OUTCH 32
#define KDIM 1280       // BBINS*INCH
#define NDIM 512        // OUTCH*TBINS
#define KSTEPS 20       // KDIM/64 (BK=64 = 4 bins)
#define MTILES 235      // ceil(NP/128)

typedef __bf16 bf16x8 __attribute__((ext_vector_type(8)));
typedef float f32x4 __attribute__((ext_vector_type(4)));

__device__ __forceinline__ void async_ld16(const void* g, void* l) {
    __builtin_amdgcn_global_load_lds(
        (const __attribute__((address_space(1))) unsigned int*)g,
        (__attribute__((address_space(3))) unsigned int*)l,
        16, 0, 0);
}

// ---------------------------------------------------------------------------
// Prep: COMPACT weights wc[bid][o][c] bf16 (80KB). Rotation (b+5t)%80 is
// realized as LDS addressing in the fused kernel. (R10-R12, refcheck-proven)
// ---------------------------------------------------------------------------
__global__ void prep_wc(const float* __restrict__ w, __bf16* __restrict__ wc) {
    int gid = blockIdx.x * 256 + threadIdx.x;            // 40960 total
    int c   = gid & 15;
    int o   = (gid >> 4) & 31;
    int bid = gid >> 9;                                  // 0..79
    wc[gid] = (__bf16)w[(bid * INCH + c) * OUTCH + o];
}

// ---------------------------------------------------------------------------
// FUSED gather+GEMM+max: R12 structure (raw barriers, vmcnt never drained,
// B LDS-resident) + BK=64 FULL-ROW GATHER UNITS.
// R12 accounting: block moves 3.3MB through CU<->L2 at the measured per-CU
// service rate ~14.8B/cy -> 93us. Meta was 1.31MB for 0.25MB payload (each
// quad read 2 rows' meta at 12B/64B-line, x2 half-redundancy). New unit:
// thread t = FULL 16-ch row (patch_l=t>>2, bin=4kc+(t&3)). Quad lanes read
// meta of 4 CONSECUTIVE bins = 48B contiguous = 1 line/quad/array, no
// redundancy: meta lines 20480 -> 5120 per block (1.31 -> 0.33MB). K-steps
// halve to 20 (half the barrier overhead). x lines unchanged (irreducible).
// A-tile: [128 patch][128B = 4bin x 16ch bf16]; 8-slot XOR swizzle
// slot_phys = s ^ (patch&7) (write: s=2tq,2tq+1; read: s=ks*4+q, row ml ->
// ml&7 covers 8 groups 2x = conflict-free both sides, verified).
// B: bid = (4kc + 2ks + (q>>1) + 5ml) % 80, byte = bid*1024 +
// ((o*2+ch)^(bid&7))*16 (R10-proven).
// ---------------------------------------------------------------------------
__global__ __launch_bounds__(512, 1) void fused_gemm_max(
    const float* __restrict__ x,
    const int*   __restrict__ cidx,
    const float* __restrict__ cval,
    const __bf16* __restrict__ wc,
    float* __restrict__ out) {

    __shared__ __align__(16) __bf16 Wlds[80 * 32 * 16];  // 80 KB, swizzled
    __shared__ __align__(16) __bf16 Alds[128 * 64];      // 16 KB (128B/patch)

    const int tid  = threadIdx.x;
    const int lane = tid & 63;
    const int wave = tid >> 6;           // 0..7
    const int wave_mrow = wave >> 2;     // 0..1
    const int wave_ncol = wave & 3;      // 0..3
    const int mbase = blockIdx.x * 128;

    // ---- Wlds fill (linear dest + involution-preswizzled src, R10-proven)
    {
        const char* src = (const char*)wc;
        char* dst = (char*)Wlds + tid * 16;
#pragma unroll
        for (int i = 0; i < 10; ++i) {
            const int byte = tid * 16 + i * 8192;
            const int bid  = byte >> 10;
            async_ld16(src + (byte ^ ((bid & 7) << 4)), dst + i * 8192);
        }
    }

    // ---- gather unit: thread = one full (patch,bin) row ----
    const int patch_l = tid >> 2;        // 0..127
    const int tq      = tid & 3;         // bin offset within k-step
    int p = mbase + patch_l;
    if (p > NP - 1) p = NP - 1;
    const int row0 = p * BBINS + tq;     // +4 per kstep
    const int pswz = (patch_l & 7);
    char* aW0 = (char*)Alds + patch_l * 128 + (((2 * tq + 0) ^ pswz) << 4);
    char* aW1 = (char*)Alds + patch_l * 128 + (((2 * tq + 1) ^ pswz) << 4);

    // ---- MFMA offsets ----
    const int ml = lane & 15, q = lane >> 4;
    int a_off[2][4];
#pragma unroll
    for (int ks = 0; ks < 2; ++ks)
#pragma unroll
        for (int i = 0; i < 4; ++i)
            a_off[ks][i] = (wave_mrow * 64 + i * 16 + ml) * 128
                         + (((ks * 4 + q) ^ (ml & 7)) << 4);
    const int ch = q & 1;
    int vj4[8];
#pragma unroll
    for (int j = 0; j < 8; ++j) {
        const int o = wave_ncol * 8 + j;
        vj4[j] = (o * 2 + ch) << 4;
    }
    int bid0 = (q >> 1) + 5 * ml;        // (4kc + 2ks + q>>1 + 5ml) % 80

    f32x4 acc[4][8];
#pragma unroll
    for (int i = 0; i < 4; ++i)
#pragma unroll
        for (int j = 0; j < 8; ++j)
            acc[i][j] = (f32x4){0.f, 0.f, 0.f, 0.f};

    // ---- gather pipeline prologue: meta(0), x(0), meta(1) ----
    int r3 = row0 * 3;
    int   ia0 = cidx[r3], ia1 = cidx[r3 + 1], ia2 = cidx[r3 + 2];
    float va0 = cval[r3], va1 = cval[r3 + 1], va2 = cval[r3 + 2];
    f32x4 xa[3][4];
    {
        const f32x4* xp0 = (const f32x4*)(x + (size_t)(unsigned)ia0 * 16);
        const f32x4* xp1 = (const f32x4*)(x + (size_t)(unsigned)ia1 * 16);
        const f32x4* xp2 = (const f32x4*)(x + (size_t)(unsigned)ia2 * 16);
#pragma unroll
        for (int u = 0; u < 4; ++u) {
            xa[0][u] = xp0[u]; xa[1][u] = xp1[u]; xa[2][u] = xp2[u];
        }
    }
    r3 = (row0 + 4) * 3;
    int   ib0 = cidx[r3], ib1 = cidx[r3 + 1], ib2 = cidx[r3 + 2];
    float vb0 = cval[r3], vb1 = cval[r3 + 1], vb2 = cval[r3 + 2];

    for (int kc = 0; kc < KSTEPS; ++kc) {
        // hv = pure VALU on preloaded x(kc); 2x ds_write_b128 (ch0-7, ch8-15)
        bf16x8 hv0, hv1;
#pragma unroll
        for (int e = 0; e < 4; ++e) {
            hv0[e]     = (__bf16)(va0 * xa[0][0][e] + va1 * xa[1][0][e] + va2 * xa[2][0][e]);
            hv0[e + 4] = (__bf16)(va0 * xa[0][1][e] + va1 * xa[1][1][e] + va2 * xa[2][1][e]);
            hv1[e]     = (__bf16)(va0 * xa[0][2][e] + va1 * xa[1][2][e] + va2 * xa[2][2][e]);
            hv1[e + 4] = (__bf16)(va0 * xa[0][3][e] + va1 * xa[1][3][e] + va2 * xa[2][3][e]);
        }
        *(bf16x8*)aW0 = hv0;
        *(bf16x8*)aW1 = hv1;

        // issue x(kc+1) via meta(kc+1); issue meta(kc+2); never drained
        f32x4 nx[3][4];
#pragma unroll
        for (int v = 0; v < 3; ++v)
#pragma unroll
            for (int u = 0; u < 4; ++u)
                nx[v][u] = xa[v][u];
        if (kc + 1 < KSTEPS) {
            const f32x4* xp0 = (const f32x4*)(x + (size_t)(unsigned)ib0 * 16);
            const f32x4* xp1 = (const f32x4*)(x + (size_t)(unsigned)ib1 * 16);
            const f32x4* xp2 = (const f32x4*)(x + (size_t)(unsigned)ib2 * 16);
#pragma unroll
            for (int u = 0; u < 4; ++u) {
                nx[0][u] = xp0[u]; nx[1][u] = xp1[u]; nx[2][u] = xp2[u];
            }
        }
        int   ni0 = ib0, ni1 = ib1, ni2 = ib2;
        float nv0 = vb0, nv1 = vb1, nv2 = vb2;
        if (kc + 2 < KSTEPS) {
            r3 = (row0 + (kc + 2) * 4) * 3;
            ni0 = cidx[r3 + 0]; ni1 = cidx[r3 + 1]; ni2 = cidx[r3 + 2];
            nv0 = cval[r3 + 0]; nv1 = cval[r3 + 1]; nv2 = cval[r3 + 2];
        }

        asm volatile("s_waitcnt lgkmcnt(0)" ::: "memory"); // my ds_writes done
        __builtin_amdgcn_s_barrier();                      // Alds (+Wlds @0) ready
        __builtin_amdgcn_sched_barrier(0);

#pragma unroll
        for (int ks = 0; ks < 2; ++ks) {
            int bid = bid0 + 2 * ks;
            if (bid >= BBINS) bid -= BBINS;
            const int bidK = bid << 10;
            const int b74  = (bid & 7) << 4;
            bf16x8 af[4], bfr[8];
#pragma unroll
            for (int i = 0; i < 4; ++i)
                af[i] = *(const bf16x8*)((const char*)Alds + a_off[ks][i]);
#pragma unroll
            for (int j = 0; j < 8; ++j)
                bfr[j] = *(const bf16x8*)((const char*)Wlds + (bidK + (vj4[j] ^ b74)));
#pragma unroll
            for (int i = 0; i < 4; ++i)
#pragma unroll
                for (int j = 0; j < 8; ++j)
                    acc[i][j] = __builtin_amdgcn_mfma_f32_16x16x32_bf16(
                        af[i], bfr[j], acc[i][j], 0, 0, 0);
        }

        asm volatile("s_waitcnt lgkmcnt(0)" ::: "memory"); // my ds_reads done
        __builtin_amdgcn_s_barrier();                      // all reads done
        __builtin_amdgcn_sched_barrier(0);

        // rotate pipeline registers
        va0 = vb0; va1 = vb1; va2 = vb2;
#pragma unroll
        for (int v = 0; v < 3; ++v)
#pragma unroll
            for (int u = 0; u < 4; ++u)
                xa[v][u] = nx[v][u];
        ib0 = ni0; ib1 = ni1; ib2 = ni2;
        vb0 = nv0; vb1 = nv1; vb2 = nv2;
        bid0 += 4;
        if (bid0 >= BBINS) bid0 -= BBINS;
    }

    const int rgrp = lane >> 4;
    const int tl   = lane & 15;
#pragma unroll
    for (int i = 0; i < 4; ++i) {
#pragma unroll
        for (int j = 0; j < 8; ++j) {
            float v0 = acc[i][j][0], v1 = acc[i][j][1];
            float v2 = acc[i][j][2], v3 = acc[i][j][3];
#pragma unroll
            for (int off = 1; off < 16; off <<= 1) {
                v0 = fmaxf(v0, __shfl_xor(v0, off));
                v1 = fmaxf(v1, __shfl_xor(v1, off));
                v2 = fmaxf(v2, __shfl_xor(v2, off));
                v3 = fmaxf(v3, __shfl_xor(v3, off));
            }
            if (tl == 0) {
                const int o  = wave_ncol * 8 + j;
                const int pr = mbase + wave_mrow * 64 + i * 16 + rgrp * 4;
                if (pr + 0 < NP) out[(pr + 0) * 32 + o] = v0;
                if (pr + 1 < NP) out[(pr + 1) * 32 + o] = v1;
                if (pr + 2 < NP) out[(pr + 2) * 32 + o] = v2;
                if (pr + 3 < NP) out[(pr + 3) * 32 + o] = v3;
            }
        }
    }
}

extern "C" void kernel_launch(void* const* d_in, const int* in_sizes, int n_in,
                              void* d_out, int out_size, void* d_ws, size_t ws_size,
                              hipStream_t stream) {
    const float* x    = (const float*)d_in[0];
    const int*   cidx = (const int*)d_in[1];
    const float* cval = (const float*)d_in[2];
    const float* w    = (const float*)d_in[3];
    float* out = (float*)d_out;

    __bf16* wc = (__bf16*)d_ws;                               // 80 KB compact

    hipLaunchKernelGGL(prep_wc, dim3(160), dim3(256), 0, stream, w, wc);
    hipLaunchKernelGGL(fused_gemm_max, dim3(MTILES), dim3(512), 0, stream,
                       x, cidx, cval, (const __bf16*)wc, out);
}

// Round 14
// 168.127 us; speedup vs baseline: 1.0415x; 1.0415x over previous
//
#include <hip/hip_runtime.h>
#include <hip/hip_bf16.h>
#include <stdint.h>

#define NP 30000
#define BBINS 80
#define INCH 16
#define OUTCH 32
#define KDIM 1280       // BBINS*INCH
#define NDIM 512        // OUTCH*TBINS
#define KSTEPS 40       // KDIM/32 (BK=32 = 2 bins)
#define MTILES 235      // ceil(NP/128)

typedef __bf16 bf16x8 __attribute__((ext_vector_type(8)));
typedef __bf16 bf16x4 __attribute__((ext_vector_type(4)));
typedef float f32x4 __attribute__((ext_vector_type(4)));

__device__ __forceinline__ void async_ld16(const void* g, void* l) {
    __builtin_amdgcn_global_load_lds(
        (const __attribute__((address_space(1))) unsigned int*)g,
        (__attribute__((address_space(3))) unsigned int*)l,
        16, 0, 0);
}

// ---------------------------------------------------------------------------
// Prep: COMPACT weights wc[bid][o][c] bf16 (80KB). Rotation (b+5t)%80 is
// realized as LDS addressing in the fused kernel. (R10-R13, refcheck-proven)
// ---------------------------------------------------------------------------
__global__ void prep_wc(const float* __restrict__ w, __bf16* __restrict__ wc) {
    int gid = blockIdx.x * 256 + threadIdx.x;            // 40960 total
    int c   = gid & 15;
    int o   = (gid >> 4) & 31;
    int bid = gid >> 9;                                  // 0..79
    wc[gid] = (__bf16)w[(bid * INCH + c) * OUTCH + o];
}

// ---------------------------------------------------------------------------
// FUSED gather+GEMM+max. Geometry/pipeline = R12 VERBATIM (93us proven:
// BK=32, raw barriers, vmcnt never drained, B LDS-resident). ONE change:
// QUAD-COOPERATIVE gather. R13 showed the wall is ISSUED L2 REQUESTS (not
// unique lines: FETCH was flat while time rose). R12 cost 18 req/quad/kstep
// (12 x + 6 meta). Now the quad (4 lanes = 1 patch) loads cooperatively:
//  * meta: all 4 lanes issue the SAME 3x int2 + 3x float2 (24B broadcast,
//    same-addr lanes merge -> 1 req/instr, 6 total; every lane gets all 6
//    values, zero shuffles).
//  * x: for each (bin b, vertex v), lane q loads chunk q of the 64B row ->
//    4 lanes = the full line = 1 request/instruction (R12: 2). 6 total.
//  * combine: lane q computes ch[4q,4q+4) of h for both bins; 2x
//    ds_write_b64 at slot (2b+(q>>1))^((u>>1)&3), sub (q&1)*8 -- verified
//    identical final layout to R12's (refcheck-proven) A read side;
//    bank analysis: 2-way max = free.
// Requests: 18 -> 12 per quad/kstep.
// ---------------------------------------------------------------------------
__global__ __launch_bounds__(512, 1) void fused_gemm_max(
    const float* __restrict__ x,
    const int*   __restrict__ cidx,
    const float* __restrict__ cval,
    const __bf16* __restrict__ wc,
    float* __restrict__ out) {

    __shared__ __align__(16) __bf16 Wlds[80 * 32 * 16];  // 80 KB, swizzled
    __shared__ __align__(16) __bf16 Alds[128 * 32];      // 8 KB (64B/patch)

    const int tid  = threadIdx.x;
    const int lane = tid & 63;
    const int wave = tid >> 6;           // 0..7
    const int wave_mrow = wave >> 2;     // 0..1
    const int wave_ncol = wave & 3;      // 0..3
    const int mbase = blockIdx.x * 128;

    // ---- Wlds fill (linear dest + involution-preswizzled src, R10-proven)
    {
        const char* src = (const char*)wc;
        char* dst = (char*)Wlds + tid * 16;
#pragma unroll
        for (int i = 0; i < 10; ++i) {
            const int byte = tid * 16 + i * 8192;
            const int bid  = byte >> 10;
            async_ld16(src + (byte ^ ((bid & 7) << 4)), dst + i * 8192);
        }
    }

    // ---- quad-cooperative gather mapping ----
    const int u = tid >> 2;              // quad = patch_l, 0..127
    const int q = tid & 3;               // chunk lane
    int p = mbase + u;
    if (p > NP - 1) p = NP - 1;
    const size_t mrow0 = (size_t)p * BBINS;      // conn row base
    const int uswz = (u >> 1) & 3;
    char* aWb0 = (char*)Alds + u * 64 + (((0 + (q >> 1)) ^ uswz) << 4) + (q & 1) * 8;
    char* aWb1 = (char*)Alds + u * 64 + (((2 + (q >> 1)) ^ uswz) << 4) + (q & 1) * 8;

#define LDMETA(s_, ii_, vv_)                                                  \
    do {                                                                      \
        const int*   ip_ = cidx + (mrow0 + 2 * (size_t)(s_)) * 3;             \
        const float* vp_ = cval + (mrow0 + 2 * (size_t)(s_)) * 3;             \
        int2 a_ = *(const int2*)(ip_);                                        \
        int2 b_ = *(const int2*)(ip_ + 2);                                    \
        int2 c_ = *(const int2*)(ip_ + 4);                                    \
        (ii_)[0] = a_.x; (ii_)[1] = a_.y; (ii_)[2] = b_.x;                    \
        (ii_)[3] = b_.y; (ii_)[4] = c_.x; (ii_)[5] = c_.y;                    \
        float2 d_ = *(const float2*)(vp_);                                    \
        float2 e_ = *(const float2*)(vp_ + 2);                                \
        float2 f_ = *(const float2*)(vp_ + 4);                                \
        (vv_)[0] = d_.x; (vv_)[1] = d_.y; (vv_)[2] = e_.x;                    \
        (vv_)[3] = e_.y; (vv_)[4] = f_.x; (vv_)[5] = f_.y;                    \
    } while (0)

#define LDX(ii_, xo_)                                                         \
    do {                                                                      \
        _Pragma("unroll")                                                     \
        for (int b_ = 0; b_ < 2; ++b_)                                        \
            _Pragma("unroll")                                                 \
            for (int v_ = 0; v_ < 3; ++v_)                                    \
                (xo_)[b_][v_] = *(const f32x4*)(                              \
                    x + (size_t)(unsigned)(ii_)[3 * b_ + v_] * 16 + q * 4);   \
    } while (0)

    // ---- MFMA offsets (R12 verbatim) ----
    const int ml = lane & 15, qw = lane >> 4;
    const int f  = (ml >> 1) & 3;
    int a_off[4];
#pragma unroll
    for (int i = 0; i < 4; ++i)
        a_off[i] = (wave_mrow * 64 + i * 16 + ml) * 64 + ((qw ^ f) << 4);
    const int ch = qw & 1;
    int vj4[8];
#pragma unroll
    for (int j = 0; j < 8; ++j) {
        const int o = wave_ncol * 8 + j;
        vj4[j] = (o * 2 + ch) << 4;
    }
    int bid = (qw >> 1) + 5 * ml;        // (2kc + qw>>1 + 5ml) % 80, kc=0

    f32x4 acc[4][8];
#pragma unroll
    for (int i = 0; i < 4; ++i)
#pragma unroll
        for (int j = 0; j < 8; ++j)
            acc[i][j] = (f32x4){0.f, 0.f, 0.f, 0.f};

    // ---- gather pipeline prologue ----
    int   icur[6]; float vcur[6];
    LDMETA(0, icur, vcur);
    f32x4 xa[2][3];
    LDX(icur, xa);
    int   inxt[6]; float vnxt[6];
    LDMETA(1, inxt, vnxt);

    for (int kc = 0; kc < KSTEPS; ++kc) {
        // combine chunk q of both bins; 2x ds_write_b64
#pragma unroll
        for (int b = 0; b < 2; ++b) {
            f32x4 s;
#pragma unroll
            for (int e = 0; e < 4; ++e)
                s[e] = vcur[3 * b + 0] * xa[b][0][e]
                     + vcur[3 * b + 1] * xa[b][1][e]
                     + vcur[3 * b + 2] * xa[b][2][e];
            bf16x4 hb;
            hb[0] = (__bf16)s[0]; hb[1] = (__bf16)s[1];
            hb[2] = (__bf16)s[2]; hb[3] = (__bf16)s[3];
            *(bf16x4*)(b ? aWb1 : aWb0) = hb;
        }

        // issue x(kc+1) via meta(kc+1); issue meta(kc+2); never drained
        f32x4 nx[2][3];
#pragma unroll
        for (int b = 0; b < 2; ++b)
#pragma unroll
            for (int v = 0; v < 3; ++v)
                nx[b][v] = xa[b][v];
        if (kc + 1 < KSTEPS)
            LDX(inxt, nx);
        int   ni[6]; float nv[6];
#pragma unroll
        for (int e = 0; e < 6; ++e) { ni[e] = inxt[e]; nv[e] = vnxt[e]; }
        if (kc + 2 < KSTEPS)
            LDMETA(kc + 2, ni, nv);

        asm volatile("s_waitcnt lgkmcnt(0)" ::: "memory"); // my ds_writes done
        __builtin_amdgcn_s_barrier();                      // Alds (+Wlds @0) ready
        __builtin_amdgcn_sched_barrier(0);

        bf16x8 af[4], bfr[8];
#pragma unroll
        for (int i = 0; i < 4; ++i)
            af[i] = *(const bf16x8*)((const char*)Alds + a_off[i]);
        const int bidK = bid << 10;
        const int b74  = (bid & 7) << 4;
#pragma unroll
        for (int j = 0; j < 8; ++j)
            bfr[j] = *(const bf16x8*)((const char*)Wlds + (bidK + (vj4[j] ^ b74)));
#pragma unroll
        for (int i = 0; i < 4; ++i)
#pragma unroll
            for (int j = 0; j < 8; ++j)
                acc[i][j] = __builtin_amdgcn_mfma_f32_16x16x32_bf16(
                    af[i], bfr[j], acc[i][j], 0, 0, 0);

        asm volatile("s_waitcnt lgkmcnt(0)" ::: "memory"); // my ds_reads done
        __builtin_amdgcn_s_barrier();                      // all reads done
        __builtin_amdgcn_sched_barrier(0);

        // rotate pipeline registers
#pragma unroll
        for (int e = 0; e < 6; ++e) {
            vcur[e] = vnxt[e];
            inxt[e] = ni[e]; vnxt[e] = nv[e];
        }
#pragma unroll
        for (int b = 0; b < 2; ++b)
#pragma unroll
            for (int v = 0; v < 3; ++v)
                xa[b][v] = nx[b][v];
        bid += 2;
        if (bid >= BBINS) bid -= BBINS;
    }
#undef LDMETA
#undef LDX

    const int rgrp = lane >> 4;
    const int tl   = lane & 15;
#pragma unroll
    for (int i = 0; i < 4; ++i) {
#pragma unroll
        for (int j = 0; j < 8; ++j) {
            float v0 = acc[i][j][0], v1 = acc[i][j][1];
            float v2 = acc[i][j][2], v3 = acc[i][j][3];
#pragma unroll
            for (int off = 1; off < 16; off <<= 1) {
                v0 = fmaxf(v0, __shfl_xor(v0, off));
                v1 = fmaxf(v1, __shfl_xor(v1, off));
                v2 = fmaxf(v2, __shfl_xor(v2, off));
                v3 = fmaxf(v3, __shfl_xor(v3, off));
            }
            if (tl == 0) {
                const int o  = wave_ncol * 8 + j;
                const int pr = mbase + wave_mrow * 64 + i * 16 + rgrp * 4;
                if (pr + 0 < NP) out[(pr + 0) * 32 + o] = v0;
                if (pr + 1 < NP) out[(pr + 1) * 32 + o] = v1;
                if (pr + 2 < NP) out[(pr + 2) * 32 + o] = v2;
                if (pr + 3 < NP) out[(pr + 3) * 32 + o] = v3;
            }
        }
    }
}

extern "C" void kernel_launch(void* const* d_in, const int* in_sizes, int n_in,
                              void* d_out, int out_size, void* d_ws, size_t ws_size,
                              hipStream_t stream) {
    const float* x    = (const float*)d_in[0];
    const int*   cidx = (const int*)d_in[1];
    const float* cval = (const float*)d_in[2];
    const float* w    = (const float*)d_in[3];
    float* out = (float*)d_out;

    __bf16* wc = (__bf16*)d_ws;                               // 80 KB compact

    hipLaunchKernelGGL(prep_wc, dim3(160), dim3(256), 0, stream, w, wc);
    hipLaunchKernelGGL(fused_gemm_max, dim3(MTILES), dim3(512), 0, stream,
                       x, cidx, cval, (const __bf16*)wc, out);
}